// Round 12
// baseline (229.425 us; speedup 1.0000x reference)
//
#include <hip/hip_runtime.h>
#include <math.h>

typedef _Float16 f16;
typedef _Float16 f16x8 __attribute__((ext_vector_type(8)));
typedef float f32x4 __attribute__((ext_vector_type(4)));

#define HEAD 128
#define EDIM 1536
#define NI   3200
#define NIP  3328
#define HDIM 768
#define BATCH 4
#define SEQ  2048
#define MTOT (BATCH*SEQ)

__device__ __forceinline__ void gld_lds16(const void* g, void* l) {
  __builtin_amdgcn_global_load_lds(
      (const __attribute__((address_space(1))) void*)g,
      (__attribute__((address_space(3))) void*)l, 16, 0, 0);
}

// ---------------- prep kernels ----------------
__global__ __launch_bounds__(256) void cast_f32_f16_k(const float* __restrict__ in,
                                                      f16* __restrict__ out, int n4) {
  int i = blockIdx.x * 256 + threadIdx.x;
  if (i >= n4) return;
  float4 x = ((const float4*)in)[i];
  union { f16 h[4]; short4 s; } u;
  u.h[0] = (f16)x.x; u.h[1] = (f16)x.y; u.h[2] = (f16)x.z; u.h[3] = (f16)x.w;
  ((short4*)out)[i] = u.s;
}

__global__ __launch_bounds__(256) void transpose_cast_k(const float* __restrict__ in, int ld_in,
                                                        f16* __restrict__ out, int ld_out) {
  __shared__ float tile[32][33];
  int c = threadIdx.x & 31, r0 = threadIdx.x >> 5;
  int ib = blockIdx.y * 32, jb = blockIdx.x * 32;
#pragma unroll
  for (int rr = 0; rr < 32; rr += 8)
    tile[r0 + rr][c] = in[(size_t)(ib + r0 + rr) * ld_in + jb + c];
  __syncthreads();
#pragma unroll
  for (int rr = 0; rr < 32; rr += 8)
    out[(size_t)(jb + r0 + rr) * ld_out + ib + c] = (f16)tile[c][r0 + rr];
}

__global__ __launch_bounds__(256) void transpose_f16_k(const f16* __restrict__ in, int ld_in,
                                                       long long sIn,
                                                       f16* __restrict__ out, int ld_out,
                                                       long long sOut) {
  __shared__ f16 tile[32][33];
  in  += (size_t)blockIdx.z * sIn;
  out += (size_t)blockIdx.z * sOut;
  int c = threadIdx.x & 31, r0 = threadIdx.x >> 5;
  int ib = blockIdx.y * 32, jb = blockIdx.x * 32;
#pragma unroll
  for (int rr = 0; rr < 32; rr += 8)
    tile[r0 + rr][c] = in[(size_t)(ib + r0 + rr) * ld_in + jb + c];
  __syncthreads();
#pragma unroll
  for (int rr = 0; rr < 32; rr += 8)
    out[(size_t)(jb + r0 + rr) * ld_out + ib + c] = tile[c][r0 + rr];
}

__global__ __launch_bounds__(256) void rope_tables_k(float* __restrict__ cosT,
                                                     float* __restrict__ sinT) {
  int id = blockIdx.x * 256 + threadIdx.x;   // < 2048*64
  int pos = id >> 6, i = id & 63;
  float ang = (float)pos / powf(10000.0f, (float)(2 * i) / 128.0f);
  float cv = cosf(ang), sv = sinf(ang);
  cosT[pos * HEAD + 2 * i]     = cv;
  cosT[pos * HEAD + 2 * i + 1] = cv;
  sinT[pos * HEAD + 2 * i]     = sv;
  sinT[pos * HEAD + 2 * i + 1] = sv;
}

__global__ __launch_bounds__(256) void addmask_k(const float* __restrict__ mask,
                                                 float* __restrict__ am) {
  int i = blockIdx.x * 256 + threadIdx.x;    // BATCH*SEQ
  am[i] = (1.0f - mask[i]) * -1e12f;
}

// ---- RoPE + OffsetScale on raw silu'd qk: qkraw[8192][128] -> Qh, Kh ----
__global__ __launch_bounds__(256) void rope_gate_k(const f16* __restrict__ qkraw,
                                                   const float* __restrict__ gamma,
                                                   const float* __restrict__ beta,
                                                   const float* __restrict__ cosT,
                                                   const float* __restrict__ sinT,
                                                   f16* __restrict__ Qh,
                                                   f16* __restrict__ Kh) {
  int id = blockIdx.x * 256 + threadIdx.x;   // 8192*16
  int row = id >> 4, c0i = (id & 15) * 8;
  int pos = row & (SEQ - 1);
  f16x8 sv8 = *(const f16x8*)(qkraw + (size_t)row * HEAD + c0i);
  f16 oq[8], ok[8];
#pragma unroll
  for (int e = 0; e < 8; e += 2) {
    int c = c0i + e;
    float cs = cosT[pos * HEAD + c], sn = sinT[pos * HEAD + c];  // pair-equal
    float s0 = (float)sv8[e], s1 = (float)sv8[e + 1];
    float q0 = s0 * gamma[c] + beta[c];
    float q1 = s1 * gamma[c + 1] + beta[c + 1];
    oq[e]     = (f16)(q0 * cs - q1 * sn);
    oq[e + 1] = (f16)(q1 * cs + q0 * sn);
    float k0 = s0 * gamma[128 + c] + beta[128 + c];
    float k1 = s1 * gamma[128 + c + 1] + beta[128 + c + 1];
    ok[e]     = (f16)(k0 * cs - k1 * sn);
    ok[e + 1] = (f16)(k1 * cs + k0 * sn);
  }
  *(f16x8*)(Qh + (size_t)row * HEAD + c0i) = *(f16x8*)oq;
  *(f16x8*)(Kh + (size_t)row * HEAD + c0i) = *(f16x8*)ok;
}

// ============ 256x256 8-wave 8-phase pipelined GEMM ============
// MODE 1: GEMM1-light -> silu; u/v -> Xh via COALESCED LDS flush; qk block (bx==12)
//         scalar path -> outH2 raw (2MB, RoPE later). Pad cols >= 3200 skipped.
// MODE 2: attn @ v; COALESCED flush; u gate loaded coalesced post-transpose.
// MODE 3: final GEMM -> f32 + bias, direct 64B-segment stores (no flush).
template <int MODE>
__global__ __launch_bounds__(512, 2)
void gemm8p(const f16* __restrict__ A, int lda,
            const f16* __restrict__ B0, int ldb, long long sB, int bshift, int K,
            f16* __restrict__ outH, f16* __restrict__ outH2,
            float* __restrict__ outF,
            const float* __restrict__ c0, const f16* __restrict__ hA) {
  __shared__ f16 LS[2][2][2][2][4096];  // [buf][mat][half][p] = 128 KiB
  int bx, by;
  {
    int gx = gridDim.x;
    int id = blockIdx.y * gx + blockIdx.x;
    int cpx = (gx * gridDim.y) >> 3;
    int sw = (id & 7) * cpx + (id >> 3);
    bx = sw % gx; by = sw / gx;
  }
  const int m0 = by * 256, n0 = bx * 256;
  const int t = threadIdx.x;
  const int lane = t & 63, w = t >> 6;
  const int wr = w >> 2, wc = w & 3;      // 2M x 4N waves; per-wave C = 128x64
  const int lr = lane & 15, kg = lane >> 4;
  const int bb = by >> bshift;
  const f16* Bb = B0 + (size_t)bb * sB;

  const int rb = t >> 3;
  const int sl = ((t & 7) ^ (rb & 7)) << 3;          // T2 swizzle (src+read pair)
  const f16* gA = A  + (size_t)(m0 + rb) * lda + sl;
  const f16* gB = Bb + (size_t)(n0 + rb) * ldb + sl;
  char* lA = (char*)LS + w * 1024;
  char* lB = (char*)LS + 32768 + w * 1024;

  auto stageA = [&](int kt, int h) {
    const f16* s = gA + (size_t)(h << 7) * lda + (kt << 6);
    char* d = lA + ((kt & 1) << 16) + (h << 14);
    gld_lds16(s, d);
    gld_lds16(s + ((size_t)lda << 6), d + 8192);
  };
  auto stageB = [&](int kt, int h) {
    const f16* s = gB + (size_t)(h << 7) * ldb + (kt << 6);
    char* d = lB + ((kt & 1) << 16) + (h << 14);
    gld_lds16(s, d);
    gld_lds16(s + ((size_t)ldb << 6), d + 8192);
  };

  const char* RA = (const char*)LS + ((wr * 128 + lr) << 7);
  const char* RB = (const char*)LS + 32768 + ((wc * 64 + lr) << 7);
  const int sw0 = (kg ^ (lr & 7)) << 4;
  const int sw1 = ((4 + kg) ^ (lr & 7)) << 4;

  f32x4 acc[8][4];
#pragma unroll
  for (int i = 0; i < 8; ++i)
#pragma unroll
    for (int j = 0; j < 4; ++j) acc[i][j] = f32x4{0.f, 0.f, 0.f, 0.f};

  const int nt = K >> 6;
  stageA(0, 0); stageA(0, 1); stageB(0, 0); stageB(0, 1);
  asm volatile("" ::: "memory");
  if (nt > 1) {
    stageB(1, 0); stageB(1, 1);
    asm volatile("s_waitcnt vmcnt(4)" ::: "memory");
  } else {
    asm volatile("s_waitcnt vmcnt(0)" ::: "memory");
  }
  __builtin_amdgcn_s_barrier();
  asm volatile("" ::: "memory");

  for (int tt = 0; tt < nt; ++tt) {
    const char* SA = RA + ((tt & 1) << 16);
    const char* SB = RB + ((tt & 1) << 16);
    f16x8 a0[4][2], a1[4][2], b0[2][2], b1[2][2];
    // phase 0: read a0,b0; stage A0(t+1); MFMA acc[0..3][0..1]
#pragma unroll
    for (int i2 = 0; i2 < 4; ++i2) {
      a0[i2][0] = *(const f16x8*)(SA + (i2 << 11) + sw0);
      a0[i2][1] = *(const f16x8*)(SA + (i2 << 11) + sw1);
    }
#pragma unroll
    for (int j2 = 0; j2 < 2; ++j2) {
      b0[j2][0] = *(const f16x8*)(SB + (j2 << 11) + sw0);
      b0[j2][1] = *(const f16x8*)(SB + (j2 << 11) + sw1);
    }
    if (tt + 1 < nt) stageA(tt + 1, 0);
    __builtin_amdgcn_s_barrier();
    asm volatile("" ::: "memory");
    __builtin_amdgcn_s_setprio(1);
#pragma unroll
    for (int ks = 0; ks < 2; ++ks)
#pragma unroll
      for (int i2 = 0; i2 < 4; ++i2)
#pragma unroll
        for (int j2 = 0; j2 < 2; ++j2)
          acc[i2][j2] = __builtin_amdgcn_mfma_f32_16x16x32_f16(
              a0[i2][ks], b0[j2][ks], acc[i2][j2], 0, 0, 0);
    __builtin_amdgcn_s_setprio(0);
    __builtin_amdgcn_s_barrier();
    asm volatile("" ::: "memory");
    // phase 1: read b1; stage A1(t+1); MFMA acc[0..3][2..3]
#pragma unroll
    for (int j2 = 0; j2 < 2; ++j2) {
      b1[j2][0] = *(const f16x8*)(SB + ((2 + j2) << 11) + sw0);
      b1[j2][1] = *(const f16x8*)(SB + ((2 + j2) << 11) + sw1);
    }
    if (tt + 1 < nt) stageA(tt + 1, 1);
    __builtin_amdgcn_s_barrier();
    asm volatile("" ::: "memory");
    __builtin_amdgcn_s_setprio(1);
#pragma unroll
    for (int ks = 0; ks < 2; ++ks)
#pragma unroll
      for (int i2 = 0; i2 < 4; ++i2)
#pragma unroll
        for (int j2 = 0; j2 < 2; ++j2)
          acc[i2][2 + j2] = __builtin_amdgcn_mfma_f32_16x16x32_f16(
              a0[i2][ks], b1[j2][ks], acc[i2][2 + j2], 0, 0, 0);
    __builtin_amdgcn_s_setprio(0);
    __builtin_amdgcn_s_barrier();
    asm volatile("" ::: "memory");
    // phase 2: read a1; stage B0(t+2); MFMA acc[4..7][0..1]
#pragma unroll
    for (int i2 = 0; i2 < 4; ++i2) {
      a1[i2][0] = *(const f16x8*)(SA + ((4 + i2) << 11) + sw0);
      a1[i2][1] = *(const f16x8*)(SA + ((4 + i2) << 11) + sw1);
    }
    if (tt + 2 < nt) stageB(tt + 2, 0);
    __builtin_amdgcn_s_barrier();
    asm volatile("" ::: "memory");
    __builtin_amdgcn_s_setprio(1);
#pragma unroll
    for (int ks = 0; ks < 2; ++ks)
#pragma unroll
      for (int i2 = 0; i2 < 4; ++i2)
#pragma unroll
        for (int j2 = 0; j2 < 2; ++j2)
          acc[4 + i2][j2] = __builtin_amdgcn_mfma_f32_16x16x32_f16(
              a1[i2][ks], b0[j2][ks], acc[4 + i2][j2], 0, 0, 0);
    __builtin_amdgcn_s_setprio(0);
    __builtin_amdgcn_s_barrier();
    asm volatile("" ::: "memory");
    // phase 3: stage B1(t+2); MFMA acc[4..7][2..3]; retire tile t+1
    if (tt + 2 < nt) stageB(tt + 2, 1);
    __builtin_amdgcn_s_barrier();
    asm volatile("" ::: "memory");
    __builtin_amdgcn_s_setprio(1);
#pragma unroll
    for (int ks = 0; ks < 2; ++ks)
#pragma unroll
      for (int i2 = 0; i2 < 4; ++i2)
#pragma unroll
        for (int j2 = 0; j2 < 2; ++j2)
          acc[4 + i2][2 + j2] = __builtin_amdgcn_mfma_f32_16x16x32_f16(
              a1[i2][ks], b1[j2][ks], acc[4 + i2][2 + j2], 0, 0, 0);
    __builtin_amdgcn_s_setprio(0);
    if (tt + 2 < nt) asm volatile("s_waitcnt vmcnt(4)" ::: "memory");
    else             asm volatile("s_waitcnt vmcnt(0)" ::: "memory");
    __builtin_amdgcn_s_barrier();
    asm volatile("" ::: "memory");
  }

  // ---- epilogue ----
  if (MODE == 3) {
    const int colbase = n0 + wc * 64;
#pragma unroll
    for (int i = 0; i < 8; ++i)
#pragma unroll
      for (int j = 0; j < 4; ++j)
#pragma unroll
        for (int r = 0; r < 4; ++r) {
          int row = m0 + wr * 128 + i * 16 + kg * 4 + r;
          int col = colbase + j * 16 + lr;
          outF[(size_t)row * HDIM + col] = acc[i][j][r] + c0[col];  // 64B segments
        }
    return;
  }
  if (MODE == 1 && bx == 12) {
    // qk block (cols 3072..3199, waves wc<2) + pad (wc>=2): scalar path, 2MB only.
    const int colbase = n0 + wc * 64;
    if (colbase >= 3200) return;
#pragma unroll
    for (int i = 0; i < 8; ++i)
#pragma unroll
      for (int j = 0; j < 4; ++j)
#pragma unroll
        for (int r = 0; r < 4; ++r) {
          int row = m0 + wr * 128 + i * 16 + kg * 4 + r;
          int col = colbase + j * 16 + lr;
          float xb = acc[i][j][r] + c0[col];
          float s = xb * __builtin_amdgcn_rcpf(1.0f + __expf(-xb));
          outH2[row * HEAD + (col - 3072)] = (f16)s;
        }
    return;
  }
  // coalesced flush: reuse LS as 256x256 f16 tile, 16B-chunk XOR swizzle (chunk ^= row&7)
  f16* OT = (f16*)LS;
#pragma unroll
  for (int i = 0; i < 8; ++i) {
#pragma unroll
    for (int j = 0; j < 4; ++j) {
#pragma unroll
      for (int r = 0; r < 4; ++r) {
        int row = wr * 128 + i * 16 + kg * 4 + r;     // local
        int col = wc * 64 + j * 16 + lr;              // local
        float x = acc[i][j][r];
        f16 v;
        if (MODE == 1) {
          float xb = x + c0[n0 + col];
          v = (f16)(xb * __builtin_amdgcn_rcpf(1.0f + __expf(-xb)));   // silu
        } else {
          v = (f16)x;                                  // gate applied at read-back
        }
        OT[row * 256 + ((((col >> 3) ^ (row & 7)) << 3) | (col & 7))] = v;
      }
    }
  }
  __syncthreads();
  const int tr = t >> 3, tc = t & 7;                   // read-back map (bank-floor)
#pragma unroll
  for (int rp = 0; rp < 4; ++rp) {
#pragma unroll
    for (int cc = 0; cc < 4; ++cc) {
      int row = rp * 64 + tr;
      int cIdx = cc * 8 + tc;
      f16x8 vv = *(const f16x8*)&OT[row * 256 + ((cIdx ^ (row & 7)) << 3)];
      if (MODE == 1) {
        *(f16x8*)&outH[(size_t)(m0 + row) * 3072 + n0 + cIdx * 8] = vv;
      } else {
        f16x8 uu = *(const f16x8*)&hA[(size_t)(m0 + row) * 3072 + n0 + cIdx * 8];
#pragma unroll
        for (int e = 0; e < 8; ++e) vv[e] = (f16)((float)vv[e] * (float)uu[e]);
        *(f16x8*)&outH[(size_t)(m0 + row) * EDIM + n0 + cIdx * 8] = vv;
      }
    }
  }
}

// ---------- scores one-shot: K=128 in LDS, T2 swizzle, coalesced f16 P flush ----------
__global__ __launch_bounds__(256, 2)
void scores_os(const f16* __restrict__ Q, const f16* __restrict__ Kt,
               f16* __restrict__ P, const float* __restrict__ am) {
  __shared__ f16 Qs[128 * 128];   // 32 KiB each
  __shared__ f16 Ks[128 * 128];
  const int z = blockIdx.z;
  const int m0 = blockIdx.y * 128, n0 = blockIdx.x * 128;
  const int t = threadIdx.x;
  const int lane = t & 63, w = t >> 6;
  const int wr = w >> 1, wc = w & 1;
  const int lr = lane & 15, kg = lane >> 4;

  const f16* Qb = Q  + (size_t)z * SEQ * HEAD;
  const f16* Kb = Kt + (size_t)z * SEQ * HEAD;

  const int rq = t >> 4, l = t & 15;
#pragma unroll
  for (int c = 0; c < 8; ++c) {
    int row = c * 16 + rq;
    int lq = l ^ (row & 15);
    gld_lds16(Qb + (size_t)(m0 + row) * HEAD + lq * 8, (char*)Qs + c * 4096 + w * 1024);
    gld_lds16(Kb + (size_t)(n0 + row) * HEAD + lq * 8, (char*)Ks + c * 4096 + w * 1024);
  }
  asm volatile("s_waitcnt vmcnt(0)" ::: "memory");
  __syncthreads();

  f32x4 acc[4][4];
#pragma unroll
  for (int i = 0; i < 4; ++i)
#pragma unroll
    for (int j = 0; j < 4; ++j) acc[i][j] = f32x4{0.f, 0.f, 0.f, 0.f};

#pragma unroll
  for (int kk = 0; kk < 4; ++kk) {
    f16x8 af[4], bf[4];
#pragma unroll
    for (int i = 0; i < 4; ++i) {
      int rA = wr * 64 + i * 16 + lr;
      af[i] = *(const f16x8*)&Qs[rA * 128 + (((kk * 4 + kg) ^ (rA & 15)) << 3)];
      int rB = wc * 64 + i * 16 + lr;
      bf[i] = *(const f16x8*)&Ks[rB * 128 + (((kk * 4 + kg) ^ (rB & 15)) << 3)];
    }
#pragma unroll
    for (int i = 0; i < 4; ++i)
#pragma unroll
      for (int j = 0; j < 4; ++j)
        acc[i][j] = __builtin_amdgcn_mfma_f32_16x16x32_f16(af[i], bf[j], acc[i][j], 0, 0, 0);
  }

  // coalesced flush via Ks (dead after MFMA): 128x128 f16, chunk XOR swizzle
  __syncthreads();
  const float* c = am + (size_t)z * SEQ;
  f16* OT = Ks;
#pragma unroll
  for (int i = 0; i < 4; ++i)
#pragma unroll
    for (int j = 0; j < 4; ++j)
#pragma unroll
      for (int r = 0; r < 4; ++r) {
        int row = wr * 64 + i * 16 + kg * 4 + r;     // local
        int col = wc * 64 + j * 16 + lr;             // local
        // -1e12 mask add overflows to f16 -inf; softmax clamps on read
        f16 v = (f16)(acc[i][j][r] * 0.08838834764831845f + c[n0 + col]);
        OT[row * 128 + ((((col >> 3) ^ (row & 7)) << 3) | (col & 7))] = v;
      }
  __syncthreads();
  f16* outP = P + (size_t)z * SEQ * SEQ;
  const int tr = t >> 3, tc = t & 7;                 // 256 thr: 32 rows x 8 chunks
#pragma unroll
  for (int rp = 0; rp < 4; ++rp) {
#pragma unroll
    for (int cc = 0; cc < 2; ++cc) {
      int row = rp * 32 + tr;
      int cIdx = cc * 8 + tc;
      f16x8 vv = *(const f16x8*)&OT[row * 128 + ((cIdx ^ (row & 7)) << 3)];
      *(f16x8*)&outP[(size_t)(m0 + row) * SEQ + n0 + cIdx * 8] = vv;
    }
  }
}

// ---------- softmax_plus on dense f16 P, in place: one block per row ----------
__global__ __launch_bounds__(256) void softmax_plus_f16(f16* __restrict__ P) {
  __shared__ float red[4];
  const int t = threadIdx.x;
  f16* pr = P + (size_t)blockIdx.x * SEQ;
  union { uint4 u4; f16 h[8]; } ld;
  ld.u4 = ((const uint4*)pr)[t];
  float v[8];
#pragma unroll
  for (int i = 0; i < 8; ++i) v[i] = fmaxf((float)ld.h[i], -1e12f);  // -inf -> -1e12

  float cnt = 0.f;
#pragma unroll
  for (int i = 0; i < 8; ++i) cnt += (v[i] > -1e11f) ? 1.0f : 0.0f;
#pragma unroll
  for (int o = 32; o; o >>= 1) cnt += __shfl_xor(cnt, o, 64);
  if ((t & 63) == 0) red[t >> 6] = cnt;
  __syncthreads();
  cnt = red[0] + red[1] + red[2] + red[3];
  float scale = __logf(fmaxf(cnt, 1.0f)) * 0.16025848f;   // 1/ln(512)

  float mx = -INFINITY;
#pragma unroll
  for (int i = 0; i < 8; ++i) { v[i] *= scale; mx = fmaxf(mx, v[i]); }
#pragma unroll
  for (int o = 32; o; o >>= 1) mx = fmaxf(mx, __shfl_xor(mx, o, 64));
  __syncthreads();
  if ((t & 63) == 0) red[t >> 6] = mx;
  __syncthreads();
  mx = fmaxf(fmaxf(red[0], red[1]), fmaxf(red[2], red[3]));

  float p[8], sum = 0.f;
#pragma unroll
  for (int i = 0; i < 8; ++i) { p[i] = __expf(v[i] - mx); sum += p[i]; }
#pragma unroll
  for (int o = 32; o; o >>= 1) sum += __shfl_xor(sum, o, 64);
  __syncthreads();
  if ((t & 63) == 0) red[t >> 6] = sum;
  __syncthreads();
  sum = red[0] + red[1] + red[2] + red[3];
  float inv = __builtin_amdgcn_rcpf(sum);

  union { f16 h[8]; uint4 u4; } pk;
#pragma unroll
  for (int i = 0; i < 8; ++i) pk.h[i] = (f16)(p[i] * inv);
  ((uint4*)pr)[t] = pk.u4;
}

// ---------------- launch ----------------
extern "C" void kernel_launch(void* const* d_in, const int* in_sizes, int n_in,
                              void* d_out, int out_size, void* d_ws, size_t ws_size,
                              hipStream_t stream) {
  const float* hs    = (const float*)d_in[0];
  const float* mask  = (const float*)d_in[1];
  const float* Wi    = (const float*)d_in[2];
  const float* bi    = (const float*)d_in[3];
  const float* gamma = (const float*)d_in[4];
  const float* beta  = (const float*)d_in[5];
  const float* Wo    = (const float*)d_in[6];
  const float* bo    = (const float*)d_in[7];
  float* out = (float*)d_out;

  const int nb = (ws_size >= ((size_t)175 << 20)) ? BATCH : 1;

  char* p = (char*)d_ws;
  auto alloc = [&](size_t b) { char* r = p; p += (b + 255) & ~(size_t)255; return r; };
  f16*   Xh    = (f16*)  alloc((size_t)MTOT * 3072 * 2);  // u|v
  f16*   qkraw = (f16*)  alloc((size_t)MTOT * HEAD * 2);  // silu'd qk, pre-RoPE
  f16*   Qh    = (f16*)  alloc((size_t)MTOT * HEAD * 2);
  f16*   Kh    = (f16*)  alloc((size_t)MTOT * HEAD * 2);
  f16*   Ah    = (f16*)  alloc((size_t)MTOT * HDIM * 2);
  f16*   WiT   = (f16*)  alloc((size_t)NIP * HDIM * 2);   // rows 3200..3327 pad (skipped)
  f16*   WoT   = (f16*)  alloc((size_t)HDIM * EDIM * 2);
  float* cosT  = (float*)alloc((size_t)SEQ * HEAD * 4);
  float* sinT  = (float*)alloc((size_t)SEQ * HEAD * 4);
  float* am    = (float*)alloc((size_t)BATCH * SEQ * 4);
  f16*   G     = (f16*)  alloc((size_t)MTOT * EDIM * 2);
  f16*   P     = (f16*)  alloc((size_t)nb * SEQ * SEQ * 2);   // dense f16 scores/attn
  f16*   Vt    = (f16*)  alloc((size_t)nb * EDIM * SEQ * 2);

  cast_f32_f16_k<<<dim3(MTOT * HDIM / 4 / 256), 256, 0, stream>>>(hs, Ah, MTOT * HDIM / 4);
  transpose_cast_k<<<dim3(NI / 32, HDIM / 32), 256, 0, stream>>>(Wi, NI, WiT, HDIM);
  transpose_cast_k<<<dim3(HDIM / 32, EDIM / 32), 256, 0, stream>>>(Wo, HDIM, WoT, EDIM);
  rope_tables_k<<<dim3(SEQ * 64 / 256), 256, 0, stream>>>(cosT, sinT);
  addmask_k<<<dim3(BATCH * SEQ / 256), 256, 0, stream>>>(mask, am);

  gemm8p<1><<<dim3(NIP / 256, MTOT / 256), 512, 0, stream>>>(
      Ah, HDIM, WiT, HDIM, 0, 30, HDIM,
      Xh, qkraw, nullptr, bi, nullptr);
  rope_gate_k<<<dim3(MTOT * 16 / 256), 256, 0, stream>>>(
      qkraw, gamma, beta, cosT, sinT, Qh, Kh);

  const int bsh = (nb == BATCH) ? 3 : 30;
  for (int b0 = 0; b0 < BATCH; b0 += nb) {
    transpose_f16_k<<<dim3(EDIM / 32, SEQ / 32, nb), 256, 0, stream>>>(
        Xh + (size_t)b0 * SEQ * 3072 + 1536, 3072, (long long)SEQ * 3072,
        Vt, SEQ, (long long)EDIM * SEQ);
    scores_os<<<dim3(SEQ / 128, SEQ / 128, nb), 256, 0, stream>>>(
        Qh + (size_t)b0 * SEQ * HEAD, Kh + (size_t)b0 * SEQ * HEAD,
        P, am + b0 * SEQ);
    softmax_plus_f16<<<dim3(nb * SEQ), 256, 0, stream>>>(P);
    gemm8p<2><<<dim3(EDIM / 256, nb * SEQ / 256), 512, 0, stream>>>(
        P, SEQ, Vt, SEQ, (long long)EDIM * SEQ, bsh, SEQ,
        G + (size_t)b0 * SEQ * EDIM, nullptr, nullptr, nullptr,
        Xh + (size_t)b0 * SEQ * 3072);
  }

  // final GEMM via 8-phase template: grid 3x32 = 96 blocks, nt = 24
  gemm8p<3><<<dim3(HDIM / 256, MTOT / 256), 512, 0, stream>>>(
      G, EDIM, WoT, EDIM, 0, 30, EDIM,
      nullptr, nullptr, out, bo, nullptr);
}

// Round 13
// 214.618 us; speedup vs baseline: 1.0690x; 1.0690x over previous
//
#include <hip/hip_runtime.h>
#include <math.h>

typedef _Float16 f16;
typedef _Float16 f16x8 __attribute__((ext_vector_type(8)));
typedef float f32x4 __attribute__((ext_vector_type(4)));

#define HEAD 128
#define EDIM 1536
#define NI   3200
#define NIP  3328
#define HDIM 768
#define BATCH 4
#define SEQ  2048
#define MTOT (BATCH*SEQ)

__device__ __forceinline__ void gld_lds16(const void* g, void* l) {
  __builtin_amdgcn_global_load_lds(
      (const __attribute__((address_space(1))) void*)g,
      (__attribute__((address_space(3))) void*)l, 16, 0, 0);
}

// ---------------- prep kernels ----------------
__global__ __launch_bounds__(256) void cast_f32_f16_k(const float* __restrict__ in,
                                                      f16* __restrict__ out, int n4) {
  int i = blockIdx.x * 256 + threadIdx.x;
  if (i >= n4) return;
  float4 x = ((const float4*)in)[i];
  union { f16 h[4]; short4 s; } u;
  u.h[0] = (f16)x.x; u.h[1] = (f16)x.y; u.h[2] = (f16)x.z; u.h[3] = (f16)x.w;
  ((short4*)out)[i] = u.s;
}

__global__ __launch_bounds__(256) void transpose_cast_k(const float* __restrict__ in, int ld_in,
                                                        f16* __restrict__ out, int ld_out) {
  __shared__ float tile[32][33];
  int c = threadIdx.x & 31, r0 = threadIdx.x >> 5;
  int ib = blockIdx.y * 32, jb = blockIdx.x * 32;
#pragma unroll
  for (int rr = 0; rr < 32; rr += 8)
    tile[r0 + rr][c] = in[(size_t)(ib + r0 + rr) * ld_in + jb + c];
  __syncthreads();
#pragma unroll
  for (int rr = 0; rr < 32; rr += 8)
    out[(size_t)(jb + r0 + rr) * ld_out + ib + c] = (f16)tile[c][r0 + rr];
}

__global__ __launch_bounds__(256) void transpose_f16_k(const f16* __restrict__ in, int ld_in,
                                                       long long sIn,
                                                       f16* __restrict__ out, int ld_out,
                                                       long long sOut) {
  __shared__ f16 tile[32][33];
  in  += (size_t)blockIdx.z * sIn;
  out += (size_t)blockIdx.z * sOut;
  int c = threadIdx.x & 31, r0 = threadIdx.x >> 5;
  int ib = blockIdx.y * 32, jb = blockIdx.x * 32;
#pragma unroll
  for (int rr = 0; rr < 32; rr += 8)
    tile[r0 + rr][c] = in[(size_t)(ib + r0 + rr) * ld_in + jb + c];
  __syncthreads();
#pragma unroll
  for (int rr = 0; rr < 32; rr += 8)
    out[(size_t)(jb + r0 + rr) * ld_out + ib + c] = tile[c][r0 + rr];
}

__global__ __launch_bounds__(256) void rope_tables_k(float* __restrict__ cosT,
                                                     float* __restrict__ sinT) {
  int id = blockIdx.x * 256 + threadIdx.x;   // < 2048*64
  int pos = id >> 6, i = id & 63;
  float ang = (float)pos / powf(10000.0f, (float)(2 * i) / 128.0f);
  float cv = cosf(ang), sv = sinf(ang);
  cosT[pos * HEAD + 2 * i]     = cv;
  cosT[pos * HEAD + 2 * i + 1] = cv;
  sinT[pos * HEAD + 2 * i]     = sv;
  sinT[pos * HEAD + 2 * i + 1] = sv;
}

__global__ __launch_bounds__(256) void addmask_k(const float* __restrict__ mask,
                                                 float* __restrict__ am) {
  int i = blockIdx.x * 256 + threadIdx.x;    // BATCH*SEQ
  am[i] = (1.0f - mask[i]) * -1e12f;
}

// ---- RoPE + OffsetScale on raw silu'd qk: qkraw[8192][128] -> Qh, Kh ----
__global__ __launch_bounds__(256) void rope_gate_k(const f16* __restrict__ qkraw,
                                                   const float* __restrict__ gamma,
                                                   const float* __restrict__ beta,
                                                   const float* __restrict__ cosT,
                                                   const float* __restrict__ sinT,
                                                   f16* __restrict__ Qh,
                                                   f16* __restrict__ Kh) {
  int id = blockIdx.x * 256 + threadIdx.x;   // 8192*16
  int row = id >> 4, c0i = (id & 15) * 8;
  int pos = row & (SEQ - 1);
  f16x8 sv8 = *(const f16x8*)(qkraw + (size_t)row * HEAD + c0i);
  f16 oq[8], ok[8];
#pragma unroll
  for (int e = 0; e < 8; e += 2) {
    int c = c0i + e;
    float cs = cosT[pos * HEAD + c], sn = sinT[pos * HEAD + c];  // pair-equal
    float s0 = (float)sv8[e], s1 = (float)sv8[e + 1];
    float q0 = s0 * gamma[c] + beta[c];
    float q1 = s1 * gamma[c + 1] + beta[c + 1];
    oq[e]     = (f16)(q0 * cs - q1 * sn);
    oq[e + 1] = (f16)(q1 * cs + q0 * sn);
    float k0 = s0 * gamma[128 + c] + beta[128 + c];
    float k1 = s1 * gamma[128 + c + 1] + beta[128 + c + 1];
    ok[e]     = (f16)(k0 * cs - k1 * sn);
    ok[e + 1] = (f16)(k1 * cs + k0 * sn);
  }
  *(f16x8*)(Qh + (size_t)row * HEAD + c0i) = *(f16x8*)oq;
  *(f16x8*)(Kh + (size_t)row * HEAD + c0i) = *(f16x8*)ok;
}

// ============ 256x256 8-wave 8-phase pipelined GEMM ============
// MODE 1: GEMM1-light -> silu; u/v -> Xh via COALESCED LDS flush (proven -17us);
//         qk block (bx==12) scalar -> outH2 raw. Pad cols >= 3200 skipped.
// MODE 2: attn @ v -> * u gate, DIRECT scalar epilogue (R10 form; flush regressed).
template <int MODE>
__global__ __launch_bounds__(512, 2)
void gemm8p(const f16* __restrict__ A, int lda,
            const f16* __restrict__ B0, int ldb, long long sB, int bshift, int K,
            f16* __restrict__ outH, f16* __restrict__ outH2,
            const float* __restrict__ c0, const f16* __restrict__ hA) {
  __shared__ f16 LS[2][2][2][2][4096];  // [buf][mat][half][p] = 128 KiB
  int bx, by;
  {
    int gx = gridDim.x;
    int id = blockIdx.y * gx + blockIdx.x;
    int cpx = (gx * gridDim.y) >> 3;
    int sw = (id & 7) * cpx + (id >> 3);
    bx = sw % gx; by = sw / gx;
  }
  const int m0 = by * 256, n0 = bx * 256;
  const int t = threadIdx.x;
  const int lane = t & 63, w = t >> 6;
  const int wr = w >> 2, wc = w & 3;      // 2M x 4N waves; per-wave C = 128x64
  const int lr = lane & 15, kg = lane >> 4;
  const int bb = by >> bshift;
  const f16* Bb = B0 + (size_t)bb * sB;

  const int rb = t >> 3;
  const int sl = ((t & 7) ^ (rb & 7)) << 3;          // T2 swizzle (src+read pair)
  const f16* gA = A  + (size_t)(m0 + rb) * lda + sl;
  const f16* gB = Bb + (size_t)(n0 + rb) * ldb + sl;
  char* lA = (char*)LS + w * 1024;
  char* lB = (char*)LS + 32768 + w * 1024;

  auto stageA = [&](int kt, int h) {
    const f16* s = gA + (size_t)(h << 7) * lda + (kt << 6);
    char* d = lA + ((kt & 1) << 16) + (h << 14);
    gld_lds16(s, d);
    gld_lds16(s + ((size_t)lda << 6), d + 8192);
  };
  auto stageB = [&](int kt, int h) {
    const f16* s = gB + (size_t)(h << 7) * ldb + (kt << 6);
    char* d = lB + ((kt & 1) << 16) + (h << 14);
    gld_lds16(s, d);
    gld_lds16(s + ((size_t)ldb << 6), d + 8192);
  };

  const char* RA = (const char*)LS + ((wr * 128 + lr) << 7);
  const char* RB = (const char*)LS + 32768 + ((wc * 64 + lr) << 7);
  const int sw0 = (kg ^ (lr & 7)) << 4;
  const int sw1 = ((4 + kg) ^ (lr & 7)) << 4;

  f32x4 acc[8][4];
#pragma unroll
  for (int i = 0; i < 8; ++i)
#pragma unroll
    for (int j = 0; j < 4; ++j) acc[i][j] = f32x4{0.f, 0.f, 0.f, 0.f};

  const int nt = K >> 6;
  stageA(0, 0); stageA(0, 1); stageB(0, 0); stageB(0, 1);
  asm volatile("" ::: "memory");
  if (nt > 1) {
    stageB(1, 0); stageB(1, 1);
    asm volatile("s_waitcnt vmcnt(4)" ::: "memory");
  } else {
    asm volatile("s_waitcnt vmcnt(0)" ::: "memory");
  }
  __builtin_amdgcn_s_barrier();
  asm volatile("" ::: "memory");

  for (int tt = 0; tt < nt; ++tt) {
    const char* SA = RA + ((tt & 1) << 16);
    const char* SB = RB + ((tt & 1) << 16);
    f16x8 a0[4][2], a1[4][2], b0[2][2], b1[2][2];
    // phase 0: read a0,b0; stage A0(t+1); MFMA acc[0..3][0..1]
#pragma unroll
    for (int i2 = 0; i2 < 4; ++i2) {
      a0[i2][0] = *(const f16x8*)(SA + (i2 << 11) + sw0);
      a0[i2][1] = *(const f16x8*)(SA + (i2 << 11) + sw1);
    }
#pragma unroll
    for (int j2 = 0; j2 < 2; ++j2) {
      b0[j2][0] = *(const f16x8*)(SB + (j2 << 11) + sw0);
      b0[j2][1] = *(const f16x8*)(SB + (j2 << 11) + sw1);
    }
    if (tt + 1 < nt) stageA(tt + 1, 0);
    __builtin_amdgcn_s_barrier();
    asm volatile("" ::: "memory");
    __builtin_amdgcn_s_setprio(1);
#pragma unroll
    for (int ks = 0; ks < 2; ++ks)
#pragma unroll
      for (int i2 = 0; i2 < 4; ++i2)
#pragma unroll
        for (int j2 = 0; j2 < 2; ++j2)
          acc[i2][j2] = __builtin_amdgcn_mfma_f32_16x16x32_f16(
              a0[i2][ks], b0[j2][ks], acc[i2][j2], 0, 0, 0);
    __builtin_amdgcn_s_setprio(0);
    __builtin_amdgcn_s_barrier();
    asm volatile("" ::: "memory");
    // phase 1: read b1; stage A1(t+1); MFMA acc[0..3][2..3]
#pragma unroll
    for (int j2 = 0; j2 < 2; ++j2) {
      b1[j2][0] = *(const f16x8*)(SB + ((2 + j2) << 11) + sw0);
      b1[j2][1] = *(const f16x8*)(SB + ((2 + j2) << 11) + sw1);
    }
    if (tt + 1 < nt) stageA(tt + 1, 1);
    __builtin_amdgcn_s_barrier();
    asm volatile("" ::: "memory");
    __builtin_amdgcn_s_setprio(1);
#pragma unroll
    for (int ks = 0; ks < 2; ++ks)
#pragma unroll
      for (int i2 = 0; i2 < 4; ++i2)
#pragma unroll
        for (int j2 = 0; j2 < 2; ++j2)
          acc[i2][2 + j2] = __builtin_amdgcn_mfma_f32_16x16x32_f16(
              a0[i2][ks], b1[j2][ks], acc[i2][2 + j2], 0, 0, 0);
    __builtin_amdgcn_s_setprio(0);
    __builtin_amdgcn_s_barrier();
    asm volatile("" ::: "memory");
    // phase 2: read a1; stage B0(t+2); MFMA acc[4..7][0..1]
#pragma unroll
    for (int i2 = 0; i2 < 4; ++i2) {
      a1[i2][0] = *(const f16x8*)(SA + ((4 + i2) << 11) + sw0);
      a1[i2][1] = *(const f16x8*)(SA + ((4 + i2) << 11) + sw1);
    }
    if (tt + 2 < nt) stageB(tt + 2, 0);
    __builtin_amdgcn_s_barrier();
    asm volatile("" ::: "memory");
    __builtin_amdgcn_s_setprio(1);
#pragma unroll
    for (int ks = 0; ks < 2; ++ks)
#pragma unroll
      for (int i2 = 0; i2 < 4; ++i2)
#pragma unroll
        for (int j2 = 0; j2 < 2; ++j2)
          acc[4 + i2][j2] = __builtin_amdgcn_mfma_f32_16x16x32_f16(
              a1[i2][ks], b0[j2][ks], acc[4 + i2][j2], 0, 0, 0);
    __builtin_amdgcn_s_setprio(0);
    __builtin_amdgcn_s_barrier();
    asm volatile("" ::: "memory");
    // phase 3: stage B1(t+2); MFMA acc[4..7][2..3]; retire tile t+1
    if (tt + 2 < nt) stageB(tt + 2, 1);
    __builtin_amdgcn_s_barrier();
    asm volatile("" ::: "memory");
    __builtin_amdgcn_s_setprio(1);
#pragma unroll
    for (int ks = 0; ks < 2; ++ks)
#pragma unroll
      for (int i2 = 0; i2 < 4; ++i2)
#pragma unroll
        for (int j2 = 0; j2 < 2; ++j2)
          acc[4 + i2][2 + j2] = __builtin_amdgcn_mfma_f32_16x16x32_f16(
              a1[i2][ks], b1[j2][ks], acc[4 + i2][2 + j2], 0, 0, 0);
    __builtin_amdgcn_s_setprio(0);
    if (tt + 2 < nt) asm volatile("s_waitcnt vmcnt(4)" ::: "memory");
    else             asm volatile("s_waitcnt vmcnt(0)" ::: "memory");
    __builtin_amdgcn_s_barrier();
    asm volatile("" ::: "memory");
  }

  // ---- epilogue ----
  if (MODE == 2) {
    // R10 form: direct scalar stores + u-gate gather (flush on PV regressed)
    const int colbase = n0 + wc * 64;
#pragma unroll
    for (int i = 0; i < 8; ++i)
#pragma unroll
      for (int j = 0; j < 4; ++j)
#pragma unroll
        for (int r = 0; r < 4; ++r) {
          int row = m0 + wr * 128 + i * 16 + kg * 4 + r;
          int col = colbase + j * 16 + lr;
          float uu = (float)hA[(size_t)row * 3072 + col];   // u gate
          outH[(size_t)row * EDIM + col] = (f16)(acc[i][j][r] * uu);
        }
    return;
  }
  if (MODE == 1 && bx == 12) {
    // qk block (cols 3072..3199, waves wc<2) + pad (wc>=2): scalar path, 2MB only.
    const int colbase = n0 + wc * 64;
    if (colbase >= 3200) return;
#pragma unroll
    for (int i = 0; i < 8; ++i)
#pragma unroll
      for (int j = 0; j < 4; ++j)
#pragma unroll
        for (int r = 0; r < 4; ++r) {
          int row = m0 + wr * 128 + i * 16 + kg * 4 + r;
          int col = colbase + j * 16 + lr;
          float xb = acc[i][j][r] + c0[col];
          float s = xb * __builtin_amdgcn_rcpf(1.0f + __expf(-xb));
          outH2[row * HEAD + (col - 3072)] = (f16)s;
        }
    return;
  }
  // MODE 1 u/v: coalesced flush (proven): reuse LS as 256x256 f16, chunk XOR swizzle
  f16* OT = (f16*)LS;
#pragma unroll
  for (int i = 0; i < 8; ++i) {
#pragma unroll
    for (int j = 0; j < 4; ++j) {
#pragma unroll
      for (int r = 0; r < 4; ++r) {
        int row = wr * 128 + i * 16 + kg * 4 + r;     // local
        int col = wc * 64 + j * 16 + lr;              // local
        float xb = acc[i][j][r] + c0[n0 + col];
        f16 v = (f16)(xb * __builtin_amdgcn_rcpf(1.0f + __expf(-xb)));   // silu
        OT[row * 256 + ((((col >> 3) ^ (row & 7)) << 3) | (col & 7))] = v;
      }
    }
  }
  __syncthreads();
  const int tr = t >> 3, tc = t & 7;                   // read-back map (bank-floor)
#pragma unroll
  for (int rp = 0; rp < 4; ++rp) {
#pragma unroll
    for (int cc = 0; cc < 4; ++cc) {
      int row = rp * 64 + tr;
      int cIdx = cc * 8 + tc;
      f16x8 vv = *(const f16x8*)&OT[row * 256 + ((cIdx ^ (row & 7)) << 3)];
      *(f16x8*)&outH[(size_t)(m0 + row) * 3072 + n0 + cIdx * 8] = vv;
    }
  }
}

// ---------- scores one-shot: K=128 in LDS, T2 swizzle, direct store (R10 form) ----------
__global__ __launch_bounds__(256, 2)
void scores_os(const f16* __restrict__ Q, const f16* __restrict__ Kt,
               f16* __restrict__ P, const float* __restrict__ am) {
  __shared__ f16 Qs[128 * 128];   // 32 KiB each
  __shared__ f16 Ks[128 * 128];
  const int z = blockIdx.z;
  const int m0 = blockIdx.y * 128, n0 = blockIdx.x * 128;
  const int t = threadIdx.x;
  const int lane = t & 63, w = t >> 6;
  const int wr = w >> 1, wc = w & 1;
  const int lr = lane & 15, kg = lane >> 4;

  const f16* Qb = Q  + (size_t)z * SEQ * HEAD;
  const f16* Kb = Kt + (size_t)z * SEQ * HEAD;

  const int rq = t >> 4, l = t & 15;
#pragma unroll
  for (int c = 0; c < 8; ++c) {
    int row = c * 16 + rq;
    int lq = l ^ (row & 15);
    gld_lds16(Qb + (size_t)(m0 + row) * HEAD + lq * 8, (char*)Qs + c * 4096 + w * 1024);
    gld_lds16(Kb + (size_t)(n0 + row) * HEAD + lq * 8, (char*)Ks + c * 4096 + w * 1024);
  }
  asm volatile("s_waitcnt vmcnt(0)" ::: "memory");
  __syncthreads();

  f32x4 acc[4][4];
#pragma unroll
  for (int i = 0; i < 4; ++i)
#pragma unroll
    for (int j = 0; j < 4; ++j) acc[i][j] = f32x4{0.f, 0.f, 0.f, 0.f};

#pragma unroll
  for (int kk = 0; kk < 4; ++kk) {
    f16x8 af[4], bf[4];
#pragma unroll
    for (int i = 0; i < 4; ++i) {
      int rA = wr * 64 + i * 16 + lr;
      af[i] = *(const f16x8*)&Qs[rA * 128 + (((kk * 4 + kg) ^ (rA & 15)) << 3)];
      int rB = wc * 64 + i * 16 + lr;
      bf[i] = *(const f16x8*)&Ks[rB * 128 + (((kk * 4 + kg) ^ (rB & 15)) << 3)];
    }
#pragma unroll
    for (int i = 0; i < 4; ++i)
#pragma unroll
      for (int j = 0; j < 4; ++j)
        acc[i][j] = __builtin_amdgcn_mfma_f32_16x16x32_f16(af[i], bf[j], acc[i][j], 0, 0, 0);
  }

  f16* outP = P + (size_t)z * SEQ * SEQ;
  const float* c = am + (size_t)z * SEQ;
#pragma unroll
  for (int i = 0; i < 4; ++i)
#pragma unroll
    for (int j = 0; j < 4; ++j)
#pragma unroll
      for (int r = 0; r < 4; ++r) {
        int row = m0 + wr * 64 + i * 16 + kg * 4 + r;
        int col = n0 + wc * 64 + j * 16 + lr;
        // -1e12 mask add overflows to f16 -inf; softmax clamps on read
        outP[(size_t)row * SEQ + col] = (f16)(acc[i][j][r] * 0.08838834764831845f + c[col]);
      }
}

// ---------- final GEMM (N=768): 128x128 2-phase dbuf + XCD swizzle (proven) ----------
__global__ __launch_bounds__(256, 4)
void gemm_final(const f16* __restrict__ A, int lda,
                const f16* __restrict__ Bt, int ldb, int K,
                float* __restrict__ outF, const float* __restrict__ c0) {
  __shared__ f16 As0[128 * 32], As1[128 * 32], Bs0[128 * 32], Bs1[128 * 32];
  int bx, by;
  {
    int gx = gridDim.x;
    int id = blockIdx.y * gx + blockIdx.x;
    int cpx = (gx * gridDim.y) >> 3;
    int sw = (id & 7) * cpx + (id >> 3);
    bx = sw % gx; by = sw / gx;
  }
  const int m0 = by * 128, n0 = bx * 128;
  const int t = threadIdx.x;
  const int lane = t & 63, w = t >> 6;
  const int wr = w >> 1, wc = w & 1;
  const int lr = lane & 15, kg = lane >> 4;

  const f16* ga = A  + (size_t)(m0 + (t >> 2)) * lda + (t & 3) * 8;
  const f16* gb = Bt + (size_t)(n0 + (t >> 2)) * ldb + (t & 3) * 8;

  f32x4 acc[4][4];
#pragma unroll
  for (int i = 0; i < 4; ++i)
#pragma unroll
    for (int j = 0; j < 4; ++j) acc[i][j] = f32x4{0.f, 0.f, 0.f, 0.f};

  auto stage = [&](f16* AS, f16* BS, int kk) {
    gld_lds16(ga + kk,                    (char*)AS + w * 1024);
    gld_lds16(ga + (size_t)64 * lda + kk, (char*)AS + w * 1024 + 4096);
    gld_lds16(gb + kk,                    (char*)BS + w * 1024);
    gld_lds16(gb + (size_t)64 * ldb + kk, (char*)BS + w * 1024 + 4096);
  };
  auto compute = [&](const f16* AS, const f16* BS) {
    f16x8 af[4], bf[4];
#pragma unroll
    for (int i = 0; i < 4; ++i) {
      af[i] = *(const f16x8*)&AS[(wr * 64 + i * 16 + lr) * 32 + kg * 8];
      bf[i] = *(const f16x8*)&BS[(wc * 64 + i * 16 + lr) * 32 + kg * 8];
    }
#pragma unroll
    for (int i = 0; i < 4; ++i)
#pragma unroll
      for (int j = 0; j < 4; ++j)
        acc[i][j] = __builtin_amdgcn_mfma_f32_16x16x32_f16(af[i], bf[j], acc[i][j], 0, 0, 0);
  };

  stage(As0, Bs0, 0);
  __syncthreads();
  for (int k0 = 0; k0 < K; k0 += 64) {
    if (k0 + 32 < K) stage(As1, Bs1, k0 + 32);
    compute(As0, Bs0);
    __syncthreads();
    if (k0 + 64 < K) stage(As0, Bs0, k0 + 64);
    compute(As1, Bs1);
    __syncthreads();
  }

#pragma unroll
  for (int i = 0; i < 4; ++i)
#pragma unroll
    for (int j = 0; j < 4; ++j)
#pragma unroll
      for (int r = 0; r < 4; ++r) {
        int row = m0 + wr * 64 + i * 16 + kg * 4 + r;
        int col = n0 + wc * 64 + j * 16 + lr;
        outF[(size_t)row * HDIM + col] = acc[i][j][r] + c0[col];
      }
}

// ---------- softmax_plus on dense f16 P, in place: one block per row ----------
__global__ __launch_bounds__(256) void softmax_plus_f16(f16* __restrict__ P) {
  __shared__ float red[4];
  const int t = threadIdx.x;
  f16* pr = P + (size_t)blockIdx.x * SEQ;
  union { uint4 u4; f16 h[8]; } ld;
  ld.u4 = ((const uint4*)pr)[t];
  float v[8];
#pragma unroll
  for (int i = 0; i < 8; ++i) v[i] = fmaxf((float)ld.h[i], -1e12f);  // -inf -> -1e12

  float cnt = 0.f;
#pragma unroll
  for (int i = 0; i < 8; ++i) cnt += (v[i] > -1e11f) ? 1.0f : 0.0f;
#pragma unroll
  for (int o = 32; o; o >>= 1) cnt += __shfl_xor(cnt, o, 64);
  if ((t & 63) == 0) red[t >> 6] = cnt;
  __syncthreads();
  cnt = red[0] + red[1] + red[2] + red[3];
  float scale = __logf(fmaxf(cnt, 1.0f)) * 0.16025848f;   // 1/ln(512)

  float mx = -INFINITY;
#pragma unroll
  for (int i = 0; i < 8; ++i) { v[i] *= scale; mx = fmaxf(mx, v[i]); }
#pragma unroll
  for (int o = 32; o; o >>= 1) mx = fmaxf(mx, __shfl_xor(mx, o, 64));
  __syncthreads();
  if ((t & 63) == 0) red[t >> 6] = mx;
  __syncthreads();
  mx = fmaxf(fmaxf(red[0], red[1]), fmaxf(red[2], red[3]));

  float p[8], sum = 0.f;
#pragma unroll
  for (int i = 0; i < 8; ++i) { p[i] = __expf(v[i] - mx); sum += p[i]; }
#pragma unroll
  for (int o = 32; o; o >>= 1) sum += __shfl_xor(sum, o, 64);
  __syncthreads();
  if ((t & 63) == 0) red[t >> 6] = sum;
  __syncthreads();
  sum = red[0] + red[1] + red[2] + red[3];
  float inv = __builtin_amdgcn_rcpf(sum);

  union { f16 h[8]; uint4 u4; } pk;
#pragma unroll
  for (int i = 0; i < 8; ++i) pk.h[i] = (f16)(p[i] * inv);
  ((uint4*)pr)[t] = pk.u4;
}

// ---------------- launch ----------------
extern "C" void kernel_launch(void* const* d_in, const int* in_sizes, int n_in,
                              void* d_out, int out_size, void* d_ws, size_t ws_size,
                              hipStream_t stream) {
  const float* hs    = (const float*)d_in[0];
  const float* mask  = (const float*)d_in[1];
  const float* Wi    = (const float*)d_in[2];
  const float* bi    = (const float*)d_in[3];
  const float* gamma = (const float*)d_in[4];
  const float* beta  = (const float*)d_in[5];
  const float* Wo    = (const float*)d_in[6];
  const float* bo    = (const float*)d_in[7];
  float* out = (float*)d_out;

  const int nb = (ws_size >= ((size_t)175 << 20)) ? BATCH : 1;

  char* p = (char*)d_ws;
  auto alloc = [&](size_t b) { char* r = p; p += (b + 255) & ~(size_t)255; return r; };
  f16*   Xh    = (f16*)  alloc((size_t)MTOT * 3072 * 2);  // u|v
  f16*   qkraw = (f16*)  alloc((size_t)MTOT * HEAD * 2);  // silu'd qk, pre-RoPE
  f16*   Qh    = (f16*)  alloc((size_t)MTOT * HEAD * 2);
  f16*   Kh    = (f16*)  alloc((size_t)MTOT * HEAD * 2);
  f16*   Ah    = (f16*)  alloc((size_t)MTOT * HDIM * 2);
  f16*   WiT   = (f16*)  alloc((size_t)NIP * HDIM * 2);   // rows 3200..3327 pad (skipped)
  f16*   WoT   = (f16*)  alloc((size_t)HDIM * EDIM * 2);
  float* cosT  = (float*)alloc((size_t)SEQ * HEAD * 4);
  float* sinT  = (float*)alloc((size_t)SEQ * HEAD * 4);
  float* am    = (float*)alloc((size_t)BATCH * SEQ * 4);
  f16*   G     = (f16*)  alloc((size_t)MTOT * EDIM * 2);
  f16*   P     = (f16*)  alloc((size_t)nb * SEQ * SEQ * 2);   // dense f16 scores/attn
  f16*   Vt    = (f16*)  alloc((size_t)nb * EDIM * SEQ * 2);

  cast_f32_f16_k<<<dim3(MTOT * HDIM / 4 / 256), 256, 0, stream>>>(hs, Ah, MTOT * HDIM / 4);
  transpose_cast_k<<<dim3(NI / 32, HDIM / 32), 256, 0, stream>>>(Wi, NI, WiT, HDIM);
  transpose_cast_k<<<dim3(HDIM / 32, EDIM / 32), 256, 0, stream>>>(Wo, HDIM, WoT, EDIM);
  rope_tables_k<<<dim3(SEQ * 64 / 256), 256, 0, stream>>>(cosT, sinT);
  addmask_k<<<dim3(BATCH * SEQ / 256), 256, 0, stream>>>(mask, am);

  gemm8p<1><<<dim3(NIP / 256, MTOT / 256), 512, 0, stream>>>(
      Ah, HDIM, WiT, HDIM, 0, 30, HDIM,
      Xh, qkraw, bi, nullptr);
  rope_gate_k<<<dim3(MTOT * 16 / 256), 256, 0, stream>>>(
      qkraw, gamma, beta, cosT, sinT, Qh, Kh);

  const int bsh = (nb == BATCH) ? 3 : 30;
  for (int b0 = 0; b0 < BATCH; b0 += nb) {
    transpose_f16_k<<<dim3(EDIM / 32, SEQ / 32, nb), 256, 0, stream>>>(
        Xh + (size_t)b0 * SEQ * 3072 + 1536, 3072, (long long)SEQ * 3072,
        Vt, SEQ, (long long)EDIM * SEQ);
    scores_os<<<dim3(SEQ / 128, SEQ / 128, nb), 256, 0, stream>>>(
        Qh + (size_t)b0 * SEQ * HEAD, Kh + (size_t)b0 * SEQ * HEAD,
        P, am + b0 * SEQ);
    softmax_plus_f16<<<dim3(nb * SEQ), 256, 0, stream>>>(P);
    gemm8p<2><<<dim3(EDIM / 256, nb * SEQ / 256), 512, 0, stream>>>(
        P, SEQ, Vt, SEQ, (long long)EDIM * SEQ, bsh, SEQ,
        G + (size_t)b0 * SEQ * EDIM, nullptr, nullptr,
        Xh + (size_t)b0 * SEQ * 3072);
  }

  gemm_final<<<dim3(HDIM / 128, MTOT / 128), 256, 0, stream>>>(
      G, EDIM, WoT, EDIM, EDIM, out, bo);
}

// Round 14
// 204.553 us; speedup vs baseline: 1.1216x; 1.0492x over previous
//
#include <hip/hip_runtime.h>
#include <math.h>

typedef _Float16 f16;
typedef _Float16 f16x8 __attribute__((ext_vector_type(8)));
typedef float f32x4 __attribute__((ext_vector_type(4)));

#define HEAD 128
#define EDIM 1536
#define NI   3200
#define NIP  3328
#define HDIM 768
#define BATCH 4
#define SEQ  2048
#define MTOT (BATCH*SEQ)

__device__ __forceinline__ void gld_lds16(const void* g, void* l) {
  __builtin_amdgcn_global_load_lds(
      (const __attribute__((address_space(1))) void*)g,
      (__attribute__((address_space(3))) void*)l, 16, 0, 0);
}

// ---------------- prep kernels ----------------
__global__ __launch_bounds__(256) void cast_f32_f16_k(const float* __restrict__ in,
                                                      f16* __restrict__ out, int n4) {
  int i = blockIdx.x * 256 + threadIdx.x;
  if (i >= n4) return;
  float4 x = ((const float4*)in)[i];
  union { f16 h[4]; short4 s; } u;
  u.h[0] = (f16)x.x; u.h[1] = (f16)x.y; u.h[2] = (f16)x.z; u.h[3] = (f16)x.w;
  ((short4*)out)[i] = u.s;
}

__global__ __launch_bounds__(256) void transpose_cast_k(const float* __restrict__ in, int ld_in,
                                                        f16* __restrict__ out, int ld_out) {
  __shared__ float tile[32][33];
  int c = threadIdx.x & 31, r0 = threadIdx.x >> 5;
  int ib = blockIdx.y * 32, jb = blockIdx.x * 32;
#pragma unroll
  for (int rr = 0; rr < 32; rr += 8)
    tile[r0 + rr][c] = in[(size_t)(ib + r0 + rr) * ld_in + jb + c];
  __syncthreads();
#pragma unroll
  for (int rr = 0; rr < 32; rr += 8)
    out[(size_t)(jb + r0 + rr) * ld_out + ib + c] = (f16)tile[c][r0 + rr];
}

__global__ __launch_bounds__(256) void rope_tables_k(float* __restrict__ cosT,
                                                     float* __restrict__ sinT) {
  int id = blockIdx.x * 256 + threadIdx.x;   // < 2048*64
  int pos = id >> 6, i = id & 63;
  float ang = (float)pos / powf(10000.0f, (float)(2 * i) / 128.0f);
  float cv = cosf(ang), sv = sinf(ang);
  cosT[pos * HEAD + 2 * i]     = cv;
  cosT[pos * HEAD + 2 * i + 1] = cv;
  sinT[pos * HEAD + 2 * i]     = sv;
  sinT[pos * HEAD + 2 * i + 1] = sv;
}

__global__ __launch_bounds__(256) void addmask_k(const float* __restrict__ mask,
                                                 float* __restrict__ am) {
  int i = blockIdx.x * 256 + threadIdx.x;    // BATCH*SEQ
  am[i] = (1.0f - mask[i]) * -1e12f;
}

// ---- RoPE + OffsetScale on raw silu'd qk: qkraw[8192][128] -> Qh, Kh ----
__global__ __launch_bounds__(256) void rope_gate_k(const f16* __restrict__ qkraw,
                                                   const float* __restrict__ gamma,
                                                   const float* __restrict__ beta,
                                                   const float* __restrict__ cosT,
                                                   const float* __restrict__ sinT,
                                                   f16* __restrict__ Qh,
                                                   f16* __restrict__ Kh) {
  int id = blockIdx.x * 256 + threadIdx.x;   // 8192*16
  int row = id >> 4, c0i = (id & 15) * 8;
  int pos = row & (SEQ - 1);
  f16x8 sv8 = *(const f16x8*)(qkraw + (size_t)row * HEAD + c0i);
  f16 oq[8], ok[8];
#pragma unroll
  for (int e = 0; e < 8; e += 2) {
    int c = c0i + e;
    float cs = cosT[pos * HEAD + c], sn = sinT[pos * HEAD + c];  // pair-equal
    float s0 = (float)sv8[e], s1 = (float)sv8[e + 1];
    float q0 = s0 * gamma[c] + beta[c];
    float q1 = s1 * gamma[c + 1] + beta[c + 1];
    oq[e]     = (f16)(q0 * cs - q1 * sn);
    oq[e + 1] = (f16)(q1 * cs + q0 * sn);
    float k0 = s0 * gamma[128 + c] + beta[128 + c];
    float k1 = s1 * gamma[128 + c + 1] + beta[128 + c + 1];
    ok[e]     = (f16)(k0 * cs - k1 * sn);
    ok[e + 1] = (f16)(k1 * cs + k0 * sn);
  }
  *(f16x8*)(Qh + (size_t)row * HEAD + c0i) = *(f16x8*)oq;
  *(f16x8*)(Kh + (size_t)row * HEAD + c0i) = *(f16x8*)ok;
}

// ============ 256x256 8-wave 8-phase pipelined GEMM ============
// MODE 1: GEMM1-light -> silu; u-blocks (bx<6) -> Xh[row][1536] via row flush;
//         v-blocks (bx 6..11) -> Vt[b][vcol][row] via COLUMN flush (kills the
//         separate transpose kernel); qk block (bx==12) scalar -> qkraw.
// MODE 2: attn @ v -> * u gate (Xh stride 1536), direct scalar epilogue.
template <int MODE>
__global__ __launch_bounds__(512, 2)
void gemm8p(const f16* __restrict__ A, int lda,
            const f16* __restrict__ B0, int ldb, long long sB, int bshift, int K,
            f16* __restrict__ outH, f16* __restrict__ outH2,
            f16* __restrict__ outV,
            const float* __restrict__ c0, const f16* __restrict__ hA) {
  __shared__ f16 LS[2][2][2][2][4096];  // [buf][mat][half][p] = 128 KiB
  int bx, by;
  {
    int gx = gridDim.x;
    int id = blockIdx.y * gx + blockIdx.x;
    int cpx = (gx * gridDim.y) >> 3;
    int sw = (id & 7) * cpx + (id >> 3);
    bx = sw % gx; by = sw / gx;
  }
  const int m0 = by * 256, n0 = bx * 256;
  const int t = threadIdx.x;
  const int lane = t & 63, w = t >> 6;
  const int wr = w >> 2, wc = w & 3;      // 2M x 4N waves; per-wave C = 128x64
  const int lr = lane & 15, kg = lane >> 4;
  const int bb = by >> bshift;
  const f16* Bb = B0 + (size_t)bb * sB;

  const int rb = t >> 3;
  const int sl = ((t & 7) ^ (rb & 7)) << 3;          // T2 swizzle (src+read pair)
  const f16* gA = A  + (size_t)(m0 + rb) * lda + sl;
  const f16* gB = Bb + (size_t)(n0 + rb) * ldb + sl;
  char* lA = (char*)LS + w * 1024;
  char* lB = (char*)LS + 32768 + w * 1024;

  auto stageA = [&](int kt, int h) {
    const f16* s = gA + (size_t)(h << 7) * lda + (kt << 6);
    char* d = lA + ((kt & 1) << 16) + (h << 14);
    gld_lds16(s, d);
    gld_lds16(s + ((size_t)lda << 6), d + 8192);
  };
  auto stageB = [&](int kt, int h) {
    const f16* s = gB + (size_t)(h << 7) * ldb + (kt << 6);
    char* d = lB + ((kt & 1) << 16) + (h << 14);
    gld_lds16(s, d);
    gld_lds16(s + ((size_t)ldb << 6), d + 8192);
  };

  const char* RA = (const char*)LS + ((wr * 128 + lr) << 7);
  const char* RB = (const char*)LS + 32768 + ((wc * 64 + lr) << 7);
  const int sw0 = (kg ^ (lr & 7)) << 4;
  const int sw1 = ((4 + kg) ^ (lr & 7)) << 4;

  f32x4 acc[8][4];
#pragma unroll
  for (int i = 0; i < 8; ++i)
#pragma unroll
    for (int j = 0; j < 4; ++j) acc[i][j] = f32x4{0.f, 0.f, 0.f, 0.f};

  const int nt = K >> 6;
  stageA(0, 0); stageA(0, 1); stageB(0, 0); stageB(0, 1);
  asm volatile("" ::: "memory");
  if (nt > 1) {
    stageB(1, 0); stageB(1, 1);
    asm volatile("s_waitcnt vmcnt(4)" ::: "memory");
  } else {
    asm volatile("s_waitcnt vmcnt(0)" ::: "memory");
  }
  __builtin_amdgcn_s_barrier();
  asm volatile("" ::: "memory");

  for (int tt = 0; tt < nt; ++tt) {
    const char* SA = RA + ((tt & 1) << 16);
    const char* SB = RB + ((tt & 1) << 16);
    f16x8 a0[4][2], a1[4][2], b0[2][2], b1[2][2];
    // phase 0: read a0,b0; stage A0(t+1); MFMA acc[0..3][0..1]
#pragma unroll
    for (int i2 = 0; i2 < 4; ++i2) {
      a0[i2][0] = *(const f16x8*)(SA + (i2 << 11) + sw0);
      a0[i2][1] = *(const f16x8*)(SA + (i2 << 11) + sw1);
    }
#pragma unroll
    for (int j2 = 0; j2 < 2; ++j2) {
      b0[j2][0] = *(const f16x8*)(SB + (j2 << 11) + sw0);
      b0[j2][1] = *(const f16x8*)(SB + (j2 << 11) + sw1);
    }
    if (tt + 1 < nt) stageA(tt + 1, 0);
    __builtin_amdgcn_s_barrier();
    asm volatile("" ::: "memory");
    __builtin_amdgcn_s_setprio(1);
#pragma unroll
    for (int ks = 0; ks < 2; ++ks)
#pragma unroll
      for (int i2 = 0; i2 < 4; ++i2)
#pragma unroll
        for (int j2 = 0; j2 < 2; ++j2)
          acc[i2][j2] = __builtin_amdgcn_mfma_f32_16x16x32_f16(
              a0[i2][ks], b0[j2][ks], acc[i2][j2], 0, 0, 0);
    __builtin_amdgcn_s_setprio(0);
    __builtin_amdgcn_s_barrier();
    asm volatile("" ::: "memory");
    // phase 1: read b1; stage A1(t+1); MFMA acc[0..3][2..3]
#pragma unroll
    for (int j2 = 0; j2 < 2; ++j2) {
      b1[j2][0] = *(const f16x8*)(SB + ((2 + j2) << 11) + sw0);
      b1[j2][1] = *(const f16x8*)(SB + ((2 + j2) << 11) + sw1);
    }
    if (tt + 1 < nt) stageA(tt + 1, 1);
    __builtin_amdgcn_s_barrier();
    asm volatile("" ::: "memory");
    __builtin_amdgcn_s_setprio(1);
#pragma unroll
    for (int ks = 0; ks < 2; ++ks)
#pragma unroll
      for (int i2 = 0; i2 < 4; ++i2)
#pragma unroll
        for (int j2 = 0; j2 < 2; ++j2)
          acc[i2][2 + j2] = __builtin_amdgcn_mfma_f32_16x16x32_f16(
              a0[i2][ks], b1[j2][ks], acc[i2][2 + j2], 0, 0, 0);
    __builtin_amdgcn_s_setprio(0);
    __builtin_amdgcn_s_barrier();
    asm volatile("" ::: "memory");
    // phase 2: read a1; stage B0(t+2); MFMA acc[4..7][0..1]
#pragma unroll
    for (int i2 = 0; i2 < 4; ++i2) {
      a1[i2][0] = *(const f16x8*)(SA + ((4 + i2) << 11) + sw0);
      a1[i2][1] = *(const f16x8*)(SA + ((4 + i2) << 11) + sw1);
    }
    if (tt + 2 < nt) stageB(tt + 2, 0);
    __builtin_amdgcn_s_barrier();
    asm volatile("" ::: "memory");
    __builtin_amdgcn_s_setprio(1);
#pragma unroll
    for (int ks = 0; ks < 2; ++ks)
#pragma unroll
      for (int i2 = 0; i2 < 4; ++i2)
#pragma unroll
        for (int j2 = 0; j2 < 2; ++j2)
          acc[4 + i2][j2] = __builtin_amdgcn_mfma_f32_16x16x32_f16(
              a1[i2][ks], b0[j2][ks], acc[4 + i2][j2], 0, 0, 0);
    __builtin_amdgcn_s_setprio(0);
    __builtin_amdgcn_s_barrier();
    asm volatile("" ::: "memory");
    // phase 3: stage B1(t+2); MFMA acc[4..7][2..3]; retire tile t+1
    if (tt + 2 < nt) stageB(tt + 2, 1);
    __builtin_amdgcn_s_barrier();
    asm volatile("" ::: "memory");
    __builtin_amdgcn_s_setprio(1);
#pragma unroll
    for (int ks = 0; ks < 2; ++ks)
#pragma unroll
      for (int i2 = 0; i2 < 4; ++i2)
#pragma unroll
        for (int j2 = 0; j2 < 2; ++j2)
          acc[4 + i2][2 + j2] = __builtin_amdgcn_mfma_f32_16x16x32_f16(
              a1[i2][ks], b1[j2][ks], acc[4 + i2][2 + j2], 0, 0, 0);
    __builtin_amdgcn_s_setprio(0);
    if (tt + 2 < nt) asm volatile("s_waitcnt vmcnt(4)" ::: "memory");
    else             asm volatile("s_waitcnt vmcnt(0)" ::: "memory");
    __builtin_amdgcn_s_barrier();
    asm volatile("" ::: "memory");
  }

  // ---- epilogue ----
  if (MODE == 2) {
    // direct scalar stores + u-gate (Xh stride 1536)
    const int colbase = n0 + wc * 64;
#pragma unroll
    for (int i = 0; i < 8; ++i)
#pragma unroll
      for (int j = 0; j < 4; ++j)
#pragma unroll
        for (int r = 0; r < 4; ++r) {
          int row = m0 + wr * 128 + i * 16 + kg * 4 + r;
          int col = colbase + j * 16 + lr;
          float uu = (float)hA[(size_t)row * EDIM + col];   // u gate
          outH[(size_t)row * EDIM + col] = (f16)(acc[i][j][r] * uu);
        }
    return;
  }
  if (MODE == 1 && bx == 12) {
    // qk block (cols 3072..3199, waves wc<2) + pad (wc>=2): scalar path, 2MB only.
    const int colbase = n0 + wc * 64;
    if (colbase >= 3200) return;
#pragma unroll
    for (int i = 0; i < 8; ++i)
#pragma unroll
      for (int j = 0; j < 4; ++j)
#pragma unroll
        for (int r = 0; r < 4; ++r) {
          int row = m0 + wr * 128 + i * 16 + kg * 4 + r;
          int col = colbase + j * 16 + lr;
          float xb = acc[i][j][r] + c0[col];
          float s = xb * __builtin_amdgcn_rcpf(1.0f + __expf(-xb));
          outH2[row * HEAD + (col - 3072)] = (f16)s;
        }
    return;
  }
  // MODE 1 u/v: flush silu'd tile into LS (dead after K-loop) with dual-use swizzle:
  // slot = (c>>3) ^ (row&7) ^ ((row>>3)&7)  -- row-readback unchanged (3rd term = 0
  // for 64-aligned row groups); column-readback spreads 32 row-groups over 8 slots.
  f16* OT = (f16*)LS;
#pragma unroll
  for (int i = 0; i < 8; ++i) {
#pragma unroll
    for (int j = 0; j < 4; ++j) {
#pragma unroll
      for (int r = 0; r < 4; ++r) {
        int row = wr * 128 + i * 16 + kg * 4 + r;     // local
        int col = wc * 64 + j * 16 + lr;              // local
        float xb = acc[i][j][r] + c0[n0 + col];
        f16 v = (f16)(xb * __builtin_amdgcn_rcpf(1.0f + __expf(-xb)));   // silu
        int slot = ((col >> 3) ^ (row & 7) ^ ((row >> 3) & 7));
        OT[row * 256 + ((slot << 3) | (col & 7))] = v;
      }
    }
  }
  __syncthreads();
  if (bx < 6) {
    // u-block: row readback, coalesced stores to Xh[row][1536]
    const int tr = t >> 3, tc = t & 7;
#pragma unroll
    for (int rp = 0; rp < 4; ++rp) {
#pragma unroll
      for (int cc = 0; cc < 4; ++cc) {
        int row = rp * 64 + tr;
        int cIdx = cc * 8 + tc;
        int slot = (cIdx ^ (row & 7) ^ ((row >> 3) & 7));
        f16x8 vv = *(const f16x8*)&OT[row * 256 + (slot << 3)];
        *(f16x8*)&outH[(size_t)(m0 + row) * EDIM + n0 + cIdx * 8] = vv;
      }
    }
  } else {
    // v-block: COLUMN readback -> Vt[b][vcol][row]; deletes the transpose kernel.
    f16* Vtb = outV + (size_t)(by >> 3) * EDIM * SEQ;
    const int vbase = n0 - EDIM;              // global v col base
    const int rib0 = m0 & (SEQ - 1);          // row-in-batch base
    const int rg = t & 31;                    // rows rg*8 .. rg*8+7
    const int cw = t >> 5;                    // 0..15; bit-swizzled col map below
    const int fm = ((cw & 1) << 2) | ((cw >> 1) & 3) | ((cw >> 3) << 3);
#pragma unroll
    for (int it = 0; it < 16; ++it) {
      int c = it * 16 + fm;
      f16 seg[8];
#pragma unroll
      for (int e = 0; e < 8; ++e) {           // row = rg*8+e; slot spreads via rg&7
        int row = rg * 8 + e;
        int slot = ((c >> 3) ^ (row & 7) ^ ((row >> 3) & 7));
        seg[e] = OT[row * 256 + ((slot << 3) | (c & 7))];
      }
      *(f16x8*)&Vtb[(size_t)(vbase + c) * SEQ + rib0 + rg * 8] = *(f16x8*)seg;
    }
  }
}

// ---------- scores one-shot: K=128 in LDS, T2 swizzle, direct store ----------
__global__ __launch_bounds__(256, 2)
void scores_os(const f16* __restrict__ Q, const f16* __restrict__ Kt,
               f16* __restrict__ P, const float* __restrict__ am) {
  __shared__ f16 Qs[128 * 128];   // 32 KiB each
  __shared__ f16 Ks[128 * 128];
  const int z = blockIdx.z;
  const int m0 = blockIdx.y * 128, n0 = blockIdx.x * 128;
  const int t = threadIdx.x;
  const int lane = t & 63, w = t >> 6;
  const int wr = w >> 1, wc = w & 1;
  const int lr = lane & 15, kg = lane >> 4;

  const f16* Qb = Q  + (size_t)z * SEQ * HEAD;
  const f16* Kb = Kt + (size_t)z * SEQ * HEAD;

  const int rq = t >> 4, l = t & 15;
#pragma unroll
  for (int c = 0; c < 8; ++c) {
    int row = c * 16 + rq;
    int lq = l ^ (row & 15);
    gld_lds16(Qb + (size_t)(m0 + row) * HEAD + lq * 8, (char*)Qs + c * 4096 + w * 1024);
    gld_lds16(Kb + (size_t)(n0 + row) * HEAD + lq * 8, (char*)Ks + c * 4096 + w * 1024);
  }
  asm volatile("s_waitcnt vmcnt(0)" ::: "memory");
  __syncthreads();

  f32x4 acc[4][4];
#pragma unroll
  for (int i = 0; i < 4; ++i)
#pragma unroll
    for (int j = 0; j < 4; ++j) acc[i][j] = f32x4{0.f, 0.f, 0.f, 0.f};

#pragma unroll
  for (int kk = 0; kk < 4; ++kk) {
    f16x8 af[4], bf[4];
#pragma unroll
    for (int i = 0; i < 4; ++i) {
      int rA = wr * 64 + i * 16 + lr;
      af[i] = *(const f16x8*)&Qs[rA * 128 + (((kk * 4 + kg) ^ (rA & 15)) << 3)];
      int rB = wc * 64 + i * 16 + lr;
      bf[i] = *(const f16x8*)&Ks[rB * 128 + (((kk * 4 + kg) ^ (rB & 15)) << 3)];
    }
#pragma unroll
    for (int i = 0; i < 4; ++i)
#pragma unroll
      for (int j = 0; j < 4; ++j)
        acc[i][j] = __builtin_amdgcn_mfma_f32_16x16x32_f16(af[i], bf[j], acc[i][j], 0, 0, 0);
  }

  f16* outP = P + (size_t)z * SEQ * SEQ;
  const float* c = am + (size_t)z * SEQ;
#pragma unroll
  for (int i = 0; i < 4; ++i)
#pragma unroll
    for (int j = 0; j < 4; ++j)
#pragma unroll
      for (int r = 0; r < 4; ++r) {
        int row = m0 + wr * 64 + i * 16 + kg * 4 + r;
        int col = n0 + wc * 64 + j * 16 + lr;
        // -1e12 mask add overflows to f16 -inf; softmax clamps on read
        outP[(size_t)row * SEQ + col] = (f16)(acc[i][j][r] * 0.08838834764831845f + c[col]);
      }
}

// ---------- final GEMM (N=768): 128x128 2-phase dbuf + XCD swizzle (proven) ----------
__global__ __launch_bounds__(256, 4)
void gemm_final(const f16* __restrict__ A, int lda,
                const f16* __restrict__ Bt, int ldb, int K,
                float* __restrict__ outF, const float* __restrict__ c0) {
  __shared__ f16 As0[128 * 32], As1[128 * 32], Bs0[128 * 32], Bs1[128 * 32];
  int bx, by;
  {
    int gx = gridDim.x;
    int id = blockIdx.y * gx + blockIdx.x;
    int cpx = (gx * gridDim.y) >> 3;
    int sw = (id & 7) * cpx + (id >> 3);
    bx = sw % gx; by = sw / gx;
  }
  const int m0 = by * 128, n0 = bx * 128;
  const int t = threadIdx.x;
  const int lane = t & 63, w = t >> 6;
  const int wr = w >> 1, wc = w & 1;
  const int lr = lane & 15, kg = lane >> 4;

  const f16* ga = A  + (size_t)(m0 + (t >> 2)) * lda + (t & 3) * 8;
  const f16* gb = Bt + (size_t)(n0 + (t >> 2)) * ldb + (t & 3) * 8;

  f32x4 acc[4][4];
#pragma unroll
  for (int i = 0; i < 4; ++i)
#pragma unroll
    for (int j = 0; j < 4; ++j) acc[i][j] = f32x4{0.f, 0.f, 0.f, 0.f};

  auto stage = [&](f16* AS, f16* BS, int kk) {
    gld_lds16(ga + kk,                    (char*)AS + w * 1024);
    gld_lds16(ga + (size_t)64 * lda + kk, (char*)AS + w * 1024 + 4096);
    gld_lds16(gb + kk,                    (char*)BS + w * 1024);
    gld_lds16(gb + (size_t)64 * ldb + kk, (char*)BS + w * 1024 + 4096);
  };
  auto compute = [&](const f16* AS, const f16* BS) {
    f16x8 af[4], bf[4];
#pragma unroll
    for (int i = 0; i < 4; ++i) {
      af[i] = *(const f16x8*)&AS[(wr * 64 + i * 16 + lr) * 32 + kg * 8];
      bf[i] = *(const f16x8*)&BS[(wc * 64 + i * 16 + lr) * 32 + kg * 8];
    }
#pragma unroll
    for (int i = 0; i < 4; ++i)
#pragma unroll
      for (int j = 0; j < 4; ++j)
        acc[i][j] = __builtin_amdgcn_mfma_f32_16x16x32_f16(af[i], bf[j], acc[i][j], 0, 0, 0);
  };

  stage(As0, Bs0, 0);
  __syncthreads();
  for (int k0 = 0; k0 < K; k0 += 64) {
    if (k0 + 32 < K) stage(As1, Bs1, k0 + 32);
    compute(As0, Bs0);
    __syncthreads();
    if (k0 + 64 < K) stage(As0, Bs0, k0 + 64);
    compute(As1, Bs1);
    __syncthreads();
  }

#pragma unroll
  for (int i = 0; i < 4; ++i)
#pragma unroll
    for (int j = 0; j < 4; ++j)
#pragma unroll
      for (int r = 0; r < 4; ++r) {
        int row = m0 + wr * 64 + i * 16 + kg * 4 + r;
        int col = n0 + wc * 64 + j * 16 + lr;
        outF[(size_t)row * HDIM + col] = acc[i][j][r] + c0[col];
      }
}

// ---------- softmax_plus on dense f16 P, in place: one block per row ----------
__global__ __launch_bounds__(256) void softmax_plus_f16(f16* __restrict__ P) {
  __shared__ float red[4];
  const int t = threadIdx.x;
  f16* pr = P + (size_t)blockIdx.x * SEQ;
  union { uint4 u4; f16 h[8]; } ld;
  ld.u4 = ((const uint4*)pr)[t];
  float v[8];
#pragma unroll
  for (int i = 0; i < 8; ++i) v[i] = fmaxf((float)ld.h[i], -1e12f);  // -inf -> -1e12

  float cnt = 0.f;
#pragma unroll
  for (int i = 0; i < 8; ++i) cnt += (v[i] > -1e11f) ? 1.0f : 0.0f;
#pragma unroll
  for (int o = 32; o; o >>= 1) cnt += __shfl_xor(cnt, o, 64);
  if ((t & 63) == 0) red[t >> 6] = cnt;
  __syncthreads();
  cnt = red[0] + red[1] + red[2] + red[3];
  float scale = __logf(fmaxf(cnt, 1.0f)) * 0.16025848f;   // 1/ln(512)

  float mx = -INFINITY;
#pragma unroll
  for (int i = 0; i < 8; ++i) { v[i] *= scale; mx = fmaxf(mx, v[i]); }
#pragma unroll
  for (int o = 32; o; o >>= 1) mx = fmaxf(mx, __shfl_xor(mx, o, 64));
  __syncthreads();
  if ((t & 63) == 0) red[t >> 6] = mx;
  __syncthreads();
  mx = fmaxf(fmaxf(red[0], red[1]), fmaxf(red[2], red[3]));

  float p[8], sum = 0.f;
#pragma unroll
  for (int i = 0; i < 8; ++i) { p[i] = __expf(v[i] - mx); sum += p[i]; }
#pragma unroll
  for (int o = 32; o; o >>= 1) sum += __shfl_xor(sum, o, 64);
  __syncthreads();
  if ((t & 63) == 0) red[t >> 6] = sum;
  __syncthreads();
  sum = red[0] + red[1] + red[2] + red[3];
  float inv = __builtin_amdgcn_rcpf(sum);

  union { f16 h[8]; uint4 u4; } pk;
#pragma unroll
  for (int i = 0; i < 8; ++i) pk.h[i] = (f16)(p[i] * inv);
  ((uint4*)pr)[t] = pk.u4;
}

// ---------------- launch ----------------
extern "C" void kernel_launch(void* const* d_in, const int* in_sizes, int n_in,
                              void* d_out, int out_size, void* d_ws, size_t ws_size,
                              hipStream_t stream) {
  const float* hs    = (const float*)d_in[0];
  const float* mask  = (const float*)d_in[1];
  const float* Wi    = (const float*)d_in[2];
  const float* bi    = (const float*)d_in[3];
  const float* gamma = (const float*)d_in[4];
  const float* beta  = (const float*)d_in[5];
  const float* Wo    = (const float*)d_in[6];
  const float* bo    = (const float*)d_in[7];
  float* out = (float*)d_out;

  const int nb = (ws_size >= ((size_t)160 << 20)) ? BATCH : 1;

  char* p = (char*)d_ws;
  auto alloc = [&](size_t b) { char* r = p; p += (b + 255) & ~(size_t)255; return r; };
  f16*   Xh    = (f16*)  alloc((size_t)MTOT * EDIM * 2);  // u only
  f16*   Vt    = (f16*)  alloc((size_t)BATCH * EDIM * SEQ * 2);  // written by GEMM1
  f16*   qkraw = (f16*)  alloc((size_t)MTOT * HEAD * 2);  // silu'd qk, pre-RoPE
  f16*   Qh    = (f16*)  alloc((size_t)MTOT * HEAD * 2);
  f16*   Kh    = (f16*)  alloc((size_t)MTOT * HEAD * 2);
  f16*   Ah    = (f16*)  alloc((size_t)MTOT * HDIM * 2);
  f16*   WiT   = (f16*)  alloc((size_t)NIP * HDIM * 2);   // rows 3200..3327 pad (skipped)
  f16*   WoT   = (f16*)  alloc((size_t)HDIM * EDIM * 2);
  float* cosT  = (float*)alloc((size_t)SEQ * HEAD * 4);
  float* sinT  = (float*)alloc((size_t)SEQ * HEAD * 4);
  float* am    = (float*)alloc((size_t)BATCH * SEQ * 4);
  f16*   G     = (f16*)  alloc((size_t)MTOT * EDIM * 2);
  f16*   P     = (f16*)  alloc((size_t)nb * SEQ * SEQ * 2);   // dense f16 scores/attn

  cast_f32_f16_k<<<dim3(MTOT * HDIM / 4 / 256), 256, 0, stream>>>(hs, Ah, MTOT * HDIM / 4);
  transpose_cast_k<<<dim3(NI / 32, HDIM / 32), 256, 0, stream>>>(Wi, NI, WiT, HDIM);
  transpose_cast_k<<<dim3(HDIM / 32, EDIM / 32), 256, 0, stream>>>(Wo, HDIM, WoT, EDIM);
  rope_tables_k<<<dim3(SEQ * 64 / 256), 256, 0, stream>>>(cosT, sinT);
  addmask_k<<<dim3(BATCH * SEQ / 256), 256, 0, stream>>>(mask, am);

  gemm8p<1><<<dim3(NIP / 256, MTOT / 256), 512, 0, stream>>>(
      Ah, HDIM, WiT, HDIM, 0, 30, HDIM,
      Xh, qkraw, Vt, bi, nullptr);
  rope_gate_k<<<dim3(MTOT * 16 / 256), 256, 0, stream>>>(
      qkraw, gamma, beta, cosT, sinT, Qh, Kh);

  const int bsh = (nb == BATCH) ? 3 : 30;
  for (int b0 = 0; b0 < BATCH; b0 += nb) {
    scores_os<<<dim3(SEQ / 128, SEQ / 128, nb), 256, 0, stream>>>(
        Qh + (size_t)b0 * SEQ * HEAD, Kh + (size_t)b0 * SEQ * HEAD,
        P, am + b0 * SEQ);
    softmax_plus_f16<<<dim3(nb * SEQ), 256, 0, stream>>>(P);
    gemm8p<2><<<dim3(EDIM / 256, nb * SEQ / 256), 512, 0, stream>>>(
        P, SEQ, Vt + (size_t)b0 * EDIM * SEQ, SEQ, (long long)EDIM * SEQ, bsh, SEQ,
        G + (size_t)b0 * SEQ * EDIM, nullptr, nullptr, nullptr,
        Xh + (size_t)b0 * SEQ * EDIM);
  }

  gemm_final<<<dim3(HDIM / 128, MTOT / 128), 256, 0, stream>>>(
      G, EDIM, WoT, EDIM, EDIM, out, bo);
}